// Round 1
// baseline (89.077 us; speedup 1.0000x reference)
//
#include <hip/hip_runtime.h>
#include <math.h>

// Weighted partial cross-entropy, MI355X.
// Single fused pass: per-class {count, masked-NLL sum} via LDS+global atomics,
// exploiting ~2% label sparsity (skip logit gather for unlabeled pixels).
// Finalize kernel computes inverse-frequency weights and the scalar loss.

constexpr int C      = 19;
constexpr int B      = 16;
constexpr int HWp    = 512 * 512;     // pixels per image = 262144 = 2^18
constexpr int LOG2HW = 18;
constexpr int NPIX   = B * HWp;       // 4,194,304

__device__ __forceinline__ void handle_pixel(const float* __restrict__ pred,
                                             int i, int t, float m,
                                             float* sS, float* sC) {
    // predictions layout [B][C][H][W]; pixel i = b*HW + hw
    const float* p = pred + (((size_t)(i >> LOG2HW) * C) << LOG2HW) + (i & (HWp - 1));
    float x[C];
    float mx = -3.4e38f, xt = 0.f;
#pragma unroll
    for (int c = 0; c < C; ++c) {              // static indices only -> registers
        float v = p[(size_t)c << LOG2HW];
        x[c] = v;
        mx = fmaxf(mx, v);
        xt = (c == t) ? v : xt;                // avoid runtime-indexed array (scratch!)
    }
    float se = 0.f;
#pragma unroll
    for (int c = 0; c < C; ++c) se += __expf(x[c] - mx);
    float nll = mx + __logf(se) - xt;          // logsumexp - x[t]
    atomicAdd(&sS[t], nll * m);
    atomicAdd(&sC[t], m);
}

__global__ void wpce_main(const float* __restrict__ pred,
                          const int4* __restrict__ tgt4,
                          const float4* __restrict__ msk4,
                          float* __restrict__ ws) {
    __shared__ float sS[C];
    __shared__ float sC[C];
    const int lt = threadIdx.x;
    if (lt < C) { sS[lt] = 0.f; sC[lt] = 0.f; }
    __syncthreads();

    const int stride = gridDim.x * blockDim.x;
    for (int v = blockIdx.x * blockDim.x + lt; v < NPIX / 4; v += stride) {
        int4   t = tgt4[v];    // coalesced 16B loads for targets/mask
        float4 m = msk4[v];
        int i0 = v * 4;
        if (m.x != 0.f) handle_pixel(pred, i0 + 0, t.x, m.x, sS, sC);
        if (m.y != 0.f) handle_pixel(pred, i0 + 1, t.y, m.y, sS, sC);
        if (m.z != 0.f) handle_pixel(pred, i0 + 2, t.z, m.z, sS, sC);
        if (m.w != 0.f) handle_pixel(pred, i0 + 3, t.w, m.w, sS, sC);
    }
    __syncthreads();
    if (lt < C) {
        atomicAdd(&ws[lt],     sS[lt]);   // S[c]   = sum of nll*m for class c
        atomicAdd(&ws[C + lt], sC[lt]);   // cnt[c] = sum of m for class c
    }
}

__global__ void wpce_fin(const float* __restrict__ ws, float* __restrict__ out) {
    const int l = threadIdx.x;   // one wave (64 lanes)
    float S   = (l < C) ? ws[l]     : 0.f;
    float cnt = (l < C) ? ws[C + l] : 0.f;

    float total = cnt;
    for (int o = 1; o < 64; o <<= 1) total += __shfl_xor(total, o);

    float w = (l < C) ? total / (cnt + 1e-6f) : 0.f;   // inverse frequency
    float sw = w;
    for (int o = 1; o < 64; o <<= 1) sw += __shfl_xor(sw, o);

    float loss = (l < C) ? (w / sw * (float)C) * S : 0.f;
    for (int o = 1; o < 64; o <<= 1) loss += __shfl_xor(loss, o);

    if (l == 0) out[0] = (total > 0.f) ? loss / total : 0.f;
}

extern "C" void kernel_launch(void* const* d_in, const int* in_sizes, int n_in,
                              void* d_out, int out_size, void* d_ws, size_t ws_size,
                              hipStream_t stream) {
    const float* pred = (const float*)d_in[0];
    const int*   tgt  = (const int*)  d_in[1];
    const float* msk  = (const float*)d_in[2];
    float* ws = (float*)d_ws;

    // d_ws is poisoned 0xAA and atomics accumulate -> zero the 38 floats each call
    hipMemsetAsync(d_ws, 0, 2 * C * sizeof(float), stream);

    const int threads = 256;
    const int blocks  = 2048;   // grid-stride; ~memory-bound cap per G11
    wpce_main<<<blocks, threads, 0, stream>>>(pred, (const int4*)tgt,
                                              (const float4*)msk, ws);
    wpce_fin<<<1, 64, 0, stream>>>(ws, (float*)d_out);
}

// Round 2
// 55.435 us; speedup vs baseline: 1.6069x; 1.6069x over previous
//
#include <hip/hip_runtime.h>
#include <math.h>

// Weighted partial cross-entropy, MI355X — 3-phase sparse pipeline.
// A: compact labeled pixels (idx|t) into a worklist  (coalesced 34MB stream)
// B: one thread per labeled pixel, 19 strided gathers, per-class {sum nll, count}
// C: inverse-frequency weights + scalar loss (one wave)

constexpr int C      = 19;
constexpr int HWp    = 512 * 512;      // 2^18 pixels per image
constexpr int LOG2HW = 18;
constexpr int NPIX   = 16 * HWp;       // 4,194,304 = 2^22  (idx fits 22 bits)
constexpr int PIXB   = 4096;           // pixels per compaction block
constexpr int ABLK   = NPIX / PIXB;    // 1024 blocks
constexpr int V4B    = PIXB / 4;       // 1024 vec4 per block

// ---------------- Phase A: stream compaction ----------------
__global__ __launch_bounds__(256) void wpce_compact(
        const int4* __restrict__ tgt4, const float4* __restrict__ msk4,
        unsigned* __restrict__ list, int* __restrict__ gcnt, int cap) {
    __shared__ unsigned ent[PIXB];     // worst-case all labeled
    __shared__ int sCnt, sBase;
    const int tid = threadIdx.x;
    if (tid == 0) sCnt = 0;
    __syncthreads();

    const int base_v = blockIdx.x * V4B;
#pragma unroll
    for (int it = 0; it < V4B / 256; ++it) {
        const int v = base_v + it * 256 + tid;
        const int4   t = tgt4[v];
        const float4 m = msk4[v];
        const unsigned i0 = (unsigned)v * 4u;
        if (m.x != 0.f) ent[atomicAdd(&sCnt, 1)] = (i0    ) | ((unsigned)t.x << 22);
        if (m.y != 0.f) ent[atomicAdd(&sCnt, 1)] = (i0 + 1) | ((unsigned)t.y << 22);
        if (m.z != 0.f) ent[atomicAdd(&sCnt, 1)] = (i0 + 2) | ((unsigned)t.z << 22);
        if (m.w != 0.f) ent[atomicAdd(&sCnt, 1)] = (i0 + 3) | ((unsigned)t.w << 22);
    }
    __syncthreads();
    if (tid == 0) sBase = atomicAdd(gcnt, sCnt);
    __syncthreads();
    const int n = sCnt, b = sBase;
    for (int i = tid; i < n; i += 256) {
        const int pos = b + i;
        if (pos < cap) list[pos] = ent[i];   // coalesced flush
    }
}

// ---------------- Phase B: sparse gather + logsumexp ----------------
__global__ __launch_bounds__(256) void wpce_gather(
        const float* __restrict__ pred, const unsigned* __restrict__ list,
        const int* __restrict__ gcnt, float* __restrict__ ws, int cap) {
    __shared__ float sS[C], sCt[C];
    const int tid = threadIdx.x;
    if (tid < C) { sS[tid] = 0.f; sCt[tid] = 0.f; }
    __syncthreads();

    const int n = min(*gcnt, cap);
    const int stride = gridDim.x * blockDim.x;
    for (int j = blockIdx.x * blockDim.x + tid; j < n; j += stride) {
        const unsigned e = list[j];
        const int idx = (int)(e & 0x3FFFFFu);
        const int t   = (int)(e >> 22);
        const float* p = pred + (((size_t)(idx >> LOG2HW) * C) << LOG2HW)
                              + (idx & (HWp - 1));
        float x[C];
        float mx = -3.4e38f, xt = 0.f;
#pragma unroll
        for (int c = 0; c < C; ++c) {          // 19 independent strided loads
            const float v = p[(size_t)c << LOG2HW];
            x[c] = v;
            mx = fmaxf(mx, v);
            xt = (c == t) ? v : xt;            // static indices only (no scratch)
        }
        float se = 0.f;
#pragma unroll
        for (int c = 0; c < C; ++c) se += __expf(x[c] - mx);
        const float nll = mx + __logf(se) - xt;
        atomicAdd(&sS[t], nll);
        atomicAdd(&sCt[t], 1.f);               // mask is exactly 1.0 when labeled
    }
    __syncthreads();
    if (tid < C && (sS[tid] != 0.f || sCt[tid] != 0.f)) {
        atomicAdd(&ws[tid],     sS[tid]);
        atomicAdd(&ws[C + tid], sCt[tid]);
    }
}

// ---------------- Phase C: finalize ----------------
__global__ void wpce_fin(const float* __restrict__ ws, float* __restrict__ out) {
    const int l = threadIdx.x;   // one wave
    float S   = (l < C) ? ws[l]     : 0.f;
    float cnt = (l < C) ? ws[C + l] : 0.f;

    float total = cnt;
    for (int o = 1; o < 64; o <<= 1) total += __shfl_xor(total, o);

    float w = (l < C) ? total / (cnt + 1e-6f) : 0.f;
    float sw = w;
    for (int o = 1; o < 64; o <<= 1) sw += __shfl_xor(sw, o);

    float loss = (l < C) ? (w / sw * (float)C) * S : 0.f;
    for (int o = 1; o < 64; o <<= 1) loss += __shfl_xor(loss, o);

    if (l == 0) out[0] = (total > 0.f) ? loss / total : 0.f;
}

extern "C" void kernel_launch(void* const* d_in, const int* in_sizes, int n_in,
                              void* d_out, int out_size, void* d_ws, size_t ws_size,
                              hipStream_t stream) {
    const float* pred = (const float*)d_in[0];
    const int*   tgt  = (const int*)  d_in[1];
    const float* msk  = (const float*)d_in[2];

    float*    ws   = (float*)d_ws;
    int*      gcnt = (int*)((char*)d_ws + 192);
    unsigned* list = (unsigned*)((char*)d_ws + 1024);
    const long capl = ((long)ws_size - 1024) / 4;
    const int  cap  = (capl > NPIX) ? NPIX : (int)capl;

    // atomics accumulate; ws poisoned 0xAA once -> zero accumulators every call
    hipMemsetAsync(d_ws, 0, 256, stream);

    wpce_compact<<<ABLK, 256, 0, stream>>>((const int4*)tgt, (const float4*)msk,
                                           list, gcnt, cap);
    // ~84k entries expected; 512 blocks x 256 covers 131k 1:1, grid-stride beyond
    wpce_gather<<<512, 256, 0, stream>>>(pred, list, gcnt, ws, cap);
    wpce_fin<<<1, 64, 0, stream>>>(ws, (float*)d_out);
}